// Round 5
// baseline (566.144 us; speedup 1.0000x reference)
//
#include <hip/hip_runtime.h>

#define N_PTS 300000
#define NPAD  300032   // multiple of 256
#define ZROW  N_PTS    // zeroed feature row used for missing neighbors

typedef _Float16 f16;
typedef _Float16 f16x8 __attribute__((ext_vector_type(8)));
typedef float    f32x4 __attribute__((ext_vector_type(4)));

__device__ __forceinline__ f16 f2h(float x) { return (f16)x; }

union u4f16 { uint4 u; f16x8 h; };

// ---------------------------------------------------------------------------
// weight prep: fp32 -> fp16 transposed.  Wt1/Wt3: [k][d][c]; Wt2b: [k][d][c2];
// Wt2a: [d2][c].   94208 = 368 * 256 threads exactly.
// ---------------------------------------------------------------------------
__global__ __launch_bounds__(256) void k_wprep(
    const float* __restrict__ W1, const float* __restrict__ W2a,
    const float* __restrict__ W2b, const float* __restrict__ W3,
    f16* __restrict__ Wt1, f16* __restrict__ Wt2a,
    f16* __restrict__ Wt2b, f16* __restrict__ Wt3)
{
    int j = blockIdx.x * 256 + threadIdx.x;
    if (j < 36864) {                       // Wt1
        int k = j >> 12, rem = j & 4095, d = rem >> 6, c = rem & 63;
        Wt1[j] = f2h(W1[(k << 12) + (c << 6) + d]);
    } else if (j < 73728) {                // Wt3
        int jj = j - 36864;
        int k = jj >> 12, rem = jj & 4095, d = rem >> 6, c = rem & 63;
        Wt3[jj] = f2h(W3[(k << 12) + (c << 6) + d]);
    } else if (j < 73728 + 18432) {        // Wt2b [k][d][c2]
        int jj = j - 73728;
        int k = jj >> 11, rem = jj & 2047, d = rem >> 5, c2 = rem & 31;
        Wt2b[jj] = f2h(W2b[k * 2048 + c2 * 64 + d]);
    } else if (j < 73728 + 18432 + 2048) { // Wt2a [d2][c]
        int jj = j - 73728 - 18432;
        int d2 = jj >> 6, c = jj & 63;
        Wt2a[jj] = f2h(W2a[c * 32 + d2]);
    }
}

// ---------------------------------------------------------------------------
// head (fused prep+bottleneck): read fp32 features once ->
//   featf fp16 (tail rows, incl. ZROW, zeroed)
//   hf = relu(bn2a(feat @ W2a)) fp16 (tail rows zeroed)
// 64 pts/wave.
// ---------------------------------------------------------------------------
__global__ __launch_bounds__(256) void k_head(
    const float* __restrict__ feat, const f16* __restrict__ Wt2a,
    const float* __restrict__ s2a, const float* __restrict__ b2a,
    f16* __restrict__ featf, f16* __restrict__ hf)
{
    int lane = threadIdx.x & 63, wave = threadIdx.x >> 6;
    int n0 = (blockIdx.x * 4 + wave) * 64;
    int ln = lane & 15, q = lane >> 4;

    f16x8 a[4][2];
#pragma unroll
    for (int mt = 0; mt < 4; mt++) {
        int n = n0 + mt * 16 + ln;
#pragma unroll
        for (int ks = 0; ks < 2; ks++) {
            u4f16 v;
            if (n < N_PTS) {
                const float* p = feat + (long)n * 64 + ks * 32 + q * 8;
                float4 lo = *(const float4*)p;
                float4 hi = *(const float4*)(p + 4);
                v.h[0] = f2h(lo.x); v.h[1] = f2h(lo.y);
                v.h[2] = f2h(lo.z); v.h[3] = f2h(lo.w);
                v.h[4] = f2h(hi.x); v.h[5] = f2h(hi.y);
                v.h[6] = f2h(hi.z); v.h[7] = f2h(hi.w);
            } else {
                v.u = make_uint4(0u, 0u, 0u, 0u);
            }
            a[mt][ks] = v.h;
            *(uint4*)(featf + (long)n * 64 + ks * 32 + q * 8) = v.u;
        }
    }

    f32x4 acc[4][2];
    for (int mt = 0; mt < 4; mt++) for (int nt = 0; nt < 2; nt++)
        acc[mt][nt] = (f32x4){0.f, 0.f, 0.f, 0.f};
#pragma unroll
    for (int ks = 0; ks < 2; ks++)
#pragma unroll
        for (int nt = 0; nt < 2; nt++) {
            f16x8 b = *(const f16x8*)(Wt2a + ((nt * 16 + ln) * 64 + ks * 32 + q * 8));
#pragma unroll
            for (int mt = 0; mt < 4; mt++)
                acc[mt][nt] = __builtin_amdgcn_mfma_f32_16x16x32_f16(a[mt][ks], b, acc[mt][nt], 0, 0, 0);
        }

#pragma unroll
    for (int nt = 0; nt < 2; nt++) {
        int ch = nt * 16 + ln;
        float s = s2a[ch], bb = b2a[ch];
#pragma unroll
        for (int mt = 0; mt < 4; mt++)
#pragma unroll
            for (int r = 0; r < 4; r++) {
                int n = n0 + mt * 16 + q * 4 + r;
                float v = (n < N_PTS) ? fmaxf(acc[mt][nt][r] * s + bb, 0.f) : 0.f;
                hf[(long)n * 32 + ch] = f2h(v);
            }
    }
}

// ---------------------------------------------------------------------------
// sparse-conv path: 32 pts/wave, all 9 tap-indices upfront (remapped to ZROW),
// depth-4 row-gather pipeline (5 rotating buffers), direct gather, no LDS.
// ---------------------------------------------------------------------------
template <int CIN>
__device__ __forceinline__ void loadrows2(
    uint4 (&dst)[2][CIN / 32], const int (&idx)[2],
    const f16* __restrict__ src, int q)
{
#pragma unroll
    for (int mt = 0; mt < 2; mt++) {
        const f16* p = src + (long)idx[mt] * CIN + q * 8;
#pragma unroll
        for (int ks = 0; ks < CIN / 32; ks++)
            dst[mt][ks] = *(const uint4*)(p + ks * 32);
    }
}

template <int CIN>
__device__ __forceinline__ void conv_path(
    const f16* __restrict__ src, const f16* __restrict__ Wt,
    const int* __restrict__ nbr,
    int lane, int n0,
    const float* __restrict__ bns, const float* __restrict__ bnb,
    f16* __restrict__ msf, int colBase, float* __restrict__ pooled)
{
    constexpr int KS = CIN / 32;
    int ln = lane & 15, q = lane >> 4;

    // all 9 taps' neighbor indices upfront; missing/pad -> ZROW (zero row)
    int idx[9][2];
#pragma unroll
    for (int k = 0; k < 9; k++) {
        const int* nb = nbr + k * N_PTS;
#pragma unroll
        for (int mt = 0; mt < 2; mt++) {
            int nn = n0 + mt * 16 + ln;
            int v = (nn < N_PTS) ? nb[nn] : -1;
            idx[k][mt] = (v < 0) ? ZROW : v;
        }
    }

    f32x4 acc[2][4];
    for (int mt = 0; mt < 2; mt++) for (int nt = 0; nt < 4; nt++)
        acc[mt][nt] = (f32x4){0.f, 0.f, 0.f, 0.f};

    uint4 raw[5][2][KS];
#pragma unroll
    for (int k = 0; k < 4; k++) loadrows2<CIN>(raw[k], idx[k], src, q);

#pragma unroll
    for (int k = 0; k < 9; k++) {
        if (k + 4 < 9) loadrows2<CIN>(raw[(k + 4) % 5], idx[k + 4], src, q);
        const f16* Wk = Wt + k * CIN * 64;
#pragma unroll
        for (int ks = 0; ks < KS; ks++)
#pragma unroll
            for (int nt = 0; nt < 4; nt++) {
                f16x8 b = *(const f16x8*)(Wk + ((nt * 16 + ln) * CIN + ks * 32 + q * 8));
#pragma unroll
                for (int mt = 0; mt < 2; mt++) {
                    u4f16 v; v.u = raw[k % 5][mt][ks];
                    acc[mt][nt] = __builtin_amdgcn_mfma_f32_16x16x32_f16(v.h, b, acc[mt][nt], 0, 0, 0);
                }
            }
    }

    // epilogue: BN + ReLU, store ms fp16, channel max -> pooled
#pragma unroll
    for (int nt = 0; nt < 4; nt++) {
        int ch = colBase + nt * 16 + ln;
        float s = bns[nt * 16 + ln], bb = bnb[nt * 16 + ln];
        float cmax = 0.f;
#pragma unroll
        for (int mt = 0; mt < 2; mt++)
#pragma unroll
            for (int r = 0; r < 4; r++) {
                int n = n0 + mt * 16 + q * 4 + r;   // always < NPAD
                float v = fmaxf(acc[mt][nt][r] * s + bb, 0.f);
                msf[(long)n * 192 + ch] = f2h(v);
                if (n < N_PTS) cmax = fmaxf(cmax, v);
            }
        cmax = fmaxf(cmax, __shfl_xor(cmax, 16));
        cmax = fmaxf(cmax, __shfl_xor(cmax, 32));
        if (q == 0) atomicMax((int*)(pooled + ch), __float_as_int(cmax));
    }
}

__global__ __launch_bounds__(256, 3) void k_conv(
    const f16* __restrict__ featf, const f16* __restrict__ hf,
    const f16* __restrict__ Wt1, const f16* __restrict__ Wt2b, const f16* __restrict__ Wt3,
    const int* __restrict__ nbr1, const int* __restrict__ nbr2,
    const float* __restrict__ bn1_s, const float* __restrict__ bn1_b,
    const float* __restrict__ bn2b_s, const float* __restrict__ bn2b_b,
    const float* __restrict__ bn3_s, const float* __restrict__ bn3_b,
    f16* __restrict__ msf, float* __restrict__ pooled)
{
    int lane = threadIdx.x & 63, wave = threadIdx.x >> 6;
    int u = blockIdx.x * 4 + wave;       // (32-pt tile, path) unit
    int tile = u / 3, path = u - tile * 3;
    int n0 = tile * 32;
    if (path == 0)
        conv_path<64>(featf, Wt1,  nbr1, lane, n0, bn1_s,  bn1_b,  msf, 0,   pooled);
    else if (path == 1)
        conv_path<32>(hf,    Wt2b, nbr1, lane, n0, bn2b_s, bn2b_b, msf, 64,  pooled);
    else
        conv_path<64>(featf, Wt3,  nbr2, lane, n0, bn3_s,  bn3_b,  msf, 128, pooled);
}

// ---------------------------------------------------------------------------
// attention MLP (1 block) + fold attn*Wf -> Wfst[d][j] fp16
// A1_w: [192,16], A2_w: [16,192]  (COUT//4 == 16)
// ---------------------------------------------------------------------------
__global__ __launch_bounds__(256) void k_attn(
    const float* __restrict__ pooled,
    const float* __restrict__ A1w, const float* __restrict__ A1b,
    const float* __restrict__ A2w, const float* __restrict__ A2b,
    const float* __restrict__ Wf, f16* __restrict__ Wfst)
{
    __shared__ float sp[192], sa1[16], sattn[192];
    int t = threadIdx.x;
    if (t < 192) sp[t] = pooled[t];
    __syncthreads();
    if (t < 16) {
        float acc = A1b[t];
        for (int i = 0; i < 192; i++) acc += sp[i] * A1w[i * 16 + t];
        sa1[t] = fmaxf(acc, 0.f);
    }
    __syncthreads();
    if (t < 192) {
        float acc = A2b[t];
        for (int i = 0; i < 16; i++) acc += sa1[i] * A2w[i * 192 + t];
        sattn[t] = 1.f / (1.f + expf(-acc));
    }
    __syncthreads();
    for (int i = t; i < 192 * 64; i += 256) {
        int d = i / 192, j = i % 192;
        Wfst[i] = f2h(Wf[j * 64 + d] * sattn[j]);
    }
}

// ---------------------------------------------------------------------------
// fusion: out = relu(bnf( ms @ (attn*Wf) ))  fp32 out.  32 pts/wave,
// all A-loads upfront, 4 waves/SIMD.
// ---------------------------------------------------------------------------
__global__ __launch_bounds__(256, 4) void k_fuse(
    const f16* __restrict__ msf, const f16* __restrict__ Wfst,
    const float* __restrict__ sf, const float* __restrict__ bf_,
    float* __restrict__ out)
{
    int lane = threadIdx.x & 63, wave = threadIdx.x >> 6;
    int n0 = (blockIdx.x * 4 + wave) * 32;
    int ln = lane & 15, q = lane >> 4;

    uint4 araw[6][2];
#pragma unroll
    for (int kt = 0; kt < 6; kt++)
#pragma unroll
        for (int mt = 0; mt < 2; mt++)
            araw[kt][mt] = *(const uint4*)(msf + (long)(n0 + mt * 16 + ln) * 192 + kt * 32 + q * 8);

    f32x4 acc[2][4];
    for (int mt = 0; mt < 2; mt++) for (int nt = 0; nt < 4; nt++)
        acc[mt][nt] = (f32x4){0.f, 0.f, 0.f, 0.f};

#pragma unroll
    for (int kt = 0; kt < 6; kt++)
#pragma unroll
        for (int nt = 0; nt < 4; nt++) {
            f16x8 b = *(const f16x8*)(Wfst + ((nt * 16 + ln) * 192 + kt * 32 + q * 8));
#pragma unroll
            for (int mt = 0; mt < 2; mt++) {
                u4f16 v; v.u = araw[kt][mt];
                acc[mt][nt] = __builtin_amdgcn_mfma_f32_16x16x32_f16(v.h, b, acc[mt][nt], 0, 0, 0);
            }
        }

#pragma unroll
    for (int nt = 0; nt < 4; nt++) {
        int ch = nt * 16 + ln;
        float s = sf[ch], bb = bf_[ch];
#pragma unroll
        for (int mt = 0; mt < 2; mt++)
#pragma unroll
            for (int r = 0; r < 4; r++) {
                int n = n0 + mt * 16 + q * 4 + r;
                if (n < N_PTS)
                    out[(long)n * 64 + ch] = fmaxf(acc[mt][nt][r] * s + bb, 0.f);
            }
    }
}

// ---------------------------------------------------------------------------
extern "C" void kernel_launch(void* const* d_in, const int* in_sizes, int n_in,
                              void* d_out, int out_size, void* d_ws, size_t ws_size,
                              hipStream_t stream)
{
    const float* features = (const float*)d_in[0];
    const float* W1     = (const float*)d_in[1];
    const float* bn1_s  = (const float*)d_in[2];
    const float* bn1_b  = (const float*)d_in[3];
    const float* W2a    = (const float*)d_in[4];
    const float* bn2a_s = (const float*)d_in[5];
    const float* bn2a_b = (const float*)d_in[6];
    const float* W2b    = (const float*)d_in[7];
    const float* bn2b_s = (const float*)d_in[8];
    const float* bn2b_b = (const float*)d_in[9];
    const float* W3     = (const float*)d_in[10];
    const float* bn3_s  = (const float*)d_in[11];
    const float* bn3_b  = (const float*)d_in[12];
    const float* A1w    = (const float*)d_in[13];
    const float* A1b    = (const float*)d_in[14];
    const float* A2w    = (const float*)d_in[15];
    const float* A2b    = (const float*)d_in[16];
    const float* Wf     = (const float*)d_in[17];
    const float* bnf_s  = (const float*)d_in[18];
    const float* bnf_b  = (const float*)d_in[19];
    const int*   nbr1   = (const int*)d_in[20];
    const int*   nbr2   = (const int*)d_in[21];

    char* ws = (char*)d_ws;
    size_t off = 0;
    f16* featf = (f16*)(ws + off); off += (size_t)NPAD * 64 * 2;
    f16* hf    = (f16*)(ws + off); off += (size_t)NPAD * 32 * 2;
    f16* msf   = (f16*)(ws + off); off += (size_t)NPAD * 192 * 2;
    f16* Wt1   = (f16*)(ws + off); off += 9 * 64 * 64 * 2;
    f16* Wt3   = (f16*)(ws + off); off += 9 * 64 * 64 * 2;
    f16* Wt2b  = (f16*)(ws + off); off += 9 * 32 * 64 * 2;
    f16* Wt2a  = (f16*)(ws + off); off += 32 * 64 * 2;
    f16* Wfst  = (f16*)(ws + off); off += 192 * 64 * 2;
    float* pooled = (float*)(ws + off); off += 256 * 4;

    hipMemsetAsync(pooled, 0, 192 * sizeof(float), stream);

    k_wprep<<<368, 256, 0, stream>>>(W1, W2a, W2b, W3, Wt1, Wt2a, Wt2b, Wt3);
    k_head<<<NPAD / 256, 256, 0, stream>>>(features, Wt2a, bn2a_s, bn2a_b, featf, hf);
    // (NPAD/32)*3 units / 4 waves per block = 7032 blocks
    k_conv<<<(NPAD / 32) * 3 / 4, 256, 0, stream>>>(featf, hf, Wt1, Wt2b, Wt3, nbr1, nbr2,
                                           bn1_s, bn1_b, bn2b_s, bn2b_b, bn3_s, bn3_b,
                                           msf, pooled);
    k_attn<<<1, 256, 0, stream>>>(pooled, A1w, A1b, A2w, A2b, Wf, Wfst);
    k_fuse<<<NPAD / 128, 256, 0, stream>>>(msf, Wfst, bnf_s, bnf_b, (float*)d_out);
}

// Round 6
// 483.133 us; speedup vs baseline: 1.1718x; 1.1718x over previous
//
#include <hip/hip_runtime.h>

#define N_PTS 300000
#define NPAD  300032   // multiple of 256
#define ZROW  N_PTS    // zeroed feature row used for missing neighbors

typedef _Float16 f16;
typedef _Float16 f16x8 __attribute__((ext_vector_type(8)));
typedef float    f32x4 __attribute__((ext_vector_type(4)));

__device__ __forceinline__ f16 f2h(float x) { return (f16)x; }

union u4f16 { uint4 u; f16x8 h; };

#define HEAD_BLOCKS (NPAD / 256)   // 1172
#define WP_BLOCKS   368            // 368*256 = 94208 weight elements

// ---------------------------------------------------------------------------
// head: fused feature-prep + bottleneck + weight transposes.
// Blocks [0, HEAD_BLOCKS): read fp32 features once ->
//   featf fp16 (tail rows incl. ZROW zeroed)
//   hf = relu(bn2a(feat @ W2a)) fp16 (tail rows zeroed); W2a converted inline.
// Blocks [HEAD_BLOCKS, HEAD_BLOCKS+WP_BLOCKS): weights -> fp16 transposed.
//   Wt1/Wt3: [k][d][c]; Wt2b: [k][d][c2]
// ---------------------------------------------------------------------------
__global__ __launch_bounds__(256) void k_head(
    const float* __restrict__ feat, const float* __restrict__ W2a,
    const float* __restrict__ s2a, const float* __restrict__ b2a,
    const float* __restrict__ W1, const float* __restrict__ W2b,
    const float* __restrict__ W3,
    f16* __restrict__ featf, f16* __restrict__ hf,
    f16* __restrict__ Wt1, f16* __restrict__ Wt2b, f16* __restrict__ Wt3)
{
    if (blockIdx.x >= HEAD_BLOCKS) {   // weight-transpose blocks
        int j = (blockIdx.x - HEAD_BLOCKS) * 256 + threadIdx.x;
        if (j < 36864) {                       // Wt1
            int k = j >> 12, rem = j & 4095, d = rem >> 6, c = rem & 63;
            Wt1[j] = f2h(W1[(k << 12) + (c << 6) + d]);
        } else if (j < 73728) {                // Wt3
            int jj = j - 36864;
            int k = jj >> 12, rem = jj & 4095, d = rem >> 6, c = rem & 63;
            Wt3[jj] = f2h(W3[(k << 12) + (c << 6) + d]);
        } else if (j < 73728 + 18432) {        // Wt2b [k][d][c2]
            int jj = j - 73728;
            int k = jj >> 11, rem = jj & 2047, d = rem >> 5, c2 = rem & 31;
            Wt2b[jj] = f2h(W2b[k * 2048 + c2 * 64 + d]);
        }
        return;
    }

    int lane = threadIdx.x & 63, wave = threadIdx.x >> 6;
    int n0 = (blockIdx.x * 4 + wave) * 64;
    int ln = lane & 15, q = lane >> 4;

    f16x8 a[4][2];
#pragma unroll
    for (int mt = 0; mt < 4; mt++) {
        int n = n0 + mt * 16 + ln;
#pragma unroll
        for (int ks = 0; ks < 2; ks++) {
            u4f16 v;
            if (n < N_PTS) {
                const float* p = feat + (long)n * 64 + ks * 32 + q * 8;
                float4 lo = *(const float4*)p;
                float4 hi = *(const float4*)(p + 4);
                v.h[0] = f2h(lo.x); v.h[1] = f2h(lo.y);
                v.h[2] = f2h(lo.z); v.h[3] = f2h(lo.w);
                v.h[4] = f2h(hi.x); v.h[5] = f2h(hi.y);
                v.h[6] = f2h(hi.z); v.h[7] = f2h(hi.w);
            } else {
                v.u = make_uint4(0u, 0u, 0u, 0u);
            }
            a[mt][ks] = v.h;
            *(uint4*)(featf + (long)n * 64 + ks * 32 + q * 8) = v.u;
        }
    }

    // B = W2a^T fragments converted inline from fp32 (8 KB, L1-resident)
    f32x4 acc[4][2];
    for (int mt = 0; mt < 4; mt++) for (int nt = 0; nt < 2; nt++)
        acc[mt][nt] = (f32x4){0.f, 0.f, 0.f, 0.f};
#pragma unroll
    for (int ks = 0; ks < 2; ks++)
#pragma unroll
        for (int nt = 0; nt < 2; nt++) {
            f16x8 b;
#pragma unroll
            for (int j = 0; j < 8; j++)
                b[j] = f2h(W2a[(ks * 32 + q * 8 + j) * 32 + nt * 16 + ln]);
#pragma unroll
            for (int mt = 0; mt < 4; mt++)
                acc[mt][nt] = __builtin_amdgcn_mfma_f32_16x16x32_f16(a[mt][ks], b, acc[mt][nt], 0, 0, 0);
        }

#pragma unroll
    for (int nt = 0; nt < 2; nt++) {
        int ch = nt * 16 + ln;
        float s = s2a[ch], bb = b2a[ch];
#pragma unroll
        for (int mt = 0; mt < 4; mt++)
#pragma unroll
            for (int r = 0; r < 4; r++) {
                int n = n0 + mt * 16 + q * 4 + r;
                float v = (n < N_PTS) ? fmaxf(acc[mt][nt][r] * s + bb, 0.f) : 0.f;
                hf[(long)n * 32 + ch] = f2h(v);
            }
    }
}

// ---------------------------------------------------------------------------
// sparse-conv path: 64 pts/wave, depth-3 row-gather pipeline (4 rotating
// buffers) + rotating idx ring (distance 4), ZROW remap, direct gather.
// ---------------------------------------------------------------------------
template <int CIN>
__device__ __forceinline__ void loadrows(
    uint4 (&dst)[4][CIN / 32], const int (&idx)[4],
    const f16* __restrict__ src, int q)
{
#pragma unroll
    for (int mt = 0; mt < 4; mt++) {
        const f16* p = src + (long)idx[mt] * CIN + q * 8;
#pragma unroll
        for (int ks = 0; ks < CIN / 32; ks++)
            dst[mt][ks] = *(const uint4*)(p + ks * 32);
    }
}

__device__ __forceinline__ void loadidx(
    int (&dst)[4], const int* __restrict__ nbr, int k, int n0, int ln)
{
    const int* nb = nbr + k * N_PTS;
#pragma unroll
    for (int mt = 0; mt < 4; mt++) {
        int nn = n0 + mt * 16 + ln;
        int v = (nn < N_PTS) ? nb[nn] : -1;
        dst[mt] = (v < 0) ? ZROW : v;
    }
}

template <int CIN>
__device__ __forceinline__ void conv_path(
    const f16* __restrict__ src, const f16* __restrict__ Wt,
    const int* __restrict__ nbr,
    int lane, int n0,
    const float* __restrict__ bns, const float* __restrict__ bnb,
    f16* __restrict__ msf, int colBase, float* __restrict__ pooled)
{
    constexpr int KS = CIN / 32;
    int ln = lane & 15, q = lane >> 4;

    f32x4 acc[4][4];
    for (int mt = 0; mt < 4; mt++) for (int nt = 0; nt < 4; nt++)
        acc[mt][nt] = (f32x4){0.f, 0.f, 0.f, 0.f};

    int  idxr[4][4];      // idx ring, distance 4
    uint4 raw[4][4][KS];  // row ring, depth 3

#pragma unroll
    for (int k = 0; k < 4; k++) loadidx(idxr[k], nbr, k, n0, ln);
#pragma unroll
    for (int k = 0; k < 3; k++) loadrows<CIN>(raw[k], idxr[k], src, q);

#pragma unroll
    for (int k = 0; k < 9; k++) {
        if (k + 3 < 9) loadrows<CIN>(raw[(k + 3) & 3], idxr[(k + 3) & 3], src, q);
        if (k + 4 < 9) loadidx(idxr[k & 3], nbr, k + 4, n0, ln);  // slot (k+4)&3 == k&3
        const f16* Wk = Wt + k * CIN * 64;
#pragma unroll
        for (int ks = 0; ks < KS; ks++)
#pragma unroll
            for (int nt = 0; nt < 4; nt++) {
                f16x8 b = *(const f16x8*)(Wk + ((nt * 16 + ln) * CIN + ks * 32 + q * 8));
#pragma unroll
                for (int mt = 0; mt < 4; mt++) {
                    u4f16 v; v.u = raw[k & 3][mt][ks];
                    acc[mt][nt] = __builtin_amdgcn_mfma_f32_16x16x32_f16(v.h, b, acc[mt][nt], 0, 0, 0);
                }
            }
    }

    // epilogue: BN + ReLU, store ms fp16, channel max -> pooled
#pragma unroll
    for (int nt = 0; nt < 4; nt++) {
        int ch = colBase + nt * 16 + ln;
        float s = bns[nt * 16 + ln], bb = bnb[nt * 16 + ln];
        float cmax = 0.f;
#pragma unroll
        for (int mt = 0; mt < 4; mt++)
#pragma unroll
            for (int r = 0; r < 4; r++) {
                int n = n0 + mt * 16 + q * 4 + r;   // always < NPAD
                float v = fmaxf(acc[mt][nt][r] * s + bb, 0.f);
                msf[(long)n * 192 + ch] = f2h(v);
                if (n < N_PTS) cmax = fmaxf(cmax, v);
            }
        cmax = fmaxf(cmax, __shfl_xor(cmax, 16));
        cmax = fmaxf(cmax, __shfl_xor(cmax, 32));
        if (q == 0) atomicMax((int*)(pooled + ch), __float_as_int(cmax));
    }
}

__global__ __launch_bounds__(256, 2) void k_conv(
    const f16* __restrict__ featf, const f16* __restrict__ hf,
    const f16* __restrict__ Wt1, const f16* __restrict__ Wt2b, const f16* __restrict__ Wt3,
    const int* __restrict__ nbr1, const int* __restrict__ nbr2,
    const float* __restrict__ bn1_s, const float* __restrict__ bn1_b,
    const float* __restrict__ bn2b_s, const float* __restrict__ bn2b_b,
    const float* __restrict__ bn3_s, const float* __restrict__ bn3_b,
    f16* __restrict__ msf, float* __restrict__ pooled)
{
    int lane = threadIdx.x & 63, wave = threadIdx.x >> 6;
    int u = blockIdx.x * 4 + wave;       // (64-pt tile, path) unit
    int tile = u / 3, path = u - tile * 3;
    int n0 = tile * 64;
    if (path == 0)
        conv_path<64>(featf, Wt1,  nbr1, lane, n0, bn1_s,  bn1_b,  msf, 0,   pooled);
    else if (path == 1)
        conv_path<32>(hf,    Wt2b, nbr1, lane, n0, bn2b_s, bn2b_b, msf, 64,  pooled);
    else
        conv_path<64>(featf, Wt3,  nbr2, lane, n0, bn3_s,  bn3_b,  msf, 128, pooled);
}

// ---------------------------------------------------------------------------
// attention MLP (1 block) + fold attn*Wf -> Wfst[d][j] fp16
// A1_w: [192,16], A2_w: [16,192]  (COUT//4 == 16)
// ---------------------------------------------------------------------------
__global__ __launch_bounds__(256) void k_attn(
    const float* __restrict__ pooled,
    const float* __restrict__ A1w, const float* __restrict__ A1b,
    const float* __restrict__ A2w, const float* __restrict__ A2b,
    const float* __restrict__ Wf, f16* __restrict__ Wfst)
{
    __shared__ float sp[192], sa1[16], sattn[192];
    int t = threadIdx.x;
    if (t < 192) sp[t] = pooled[t];
    __syncthreads();
    if (t < 16) {
        float acc = A1b[t];
        for (int i = 0; i < 192; i++) acc += sp[i] * A1w[i * 16 + t];
        sa1[t] = fmaxf(acc, 0.f);
    }
    __syncthreads();
    if (t < 192) {
        float acc = A2b[t];
        for (int i = 0; i < 16; i++) acc += sa1[i] * A2w[i * 192 + t];
        sattn[t] = 1.f / (1.f + expf(-acc));
    }
    __syncthreads();
    for (int i = t; i < 192 * 64; i += 256) {
        int d = i / 192, j = i % 192;
        Wfst[i] = f2h(Wf[j * 64 + d] * sattn[j]);
    }
}

// ---------------------------------------------------------------------------
// fusion: out = relu(bnf( ms @ (attn*Wf) ))  fp32 out.  32 pts/wave,
// all A-loads upfront, 4 waves/SIMD.
// ---------------------------------------------------------------------------
__global__ __launch_bounds__(256, 4) void k_fuse(
    const f16* __restrict__ msf, const f16* __restrict__ Wfst,
    const float* __restrict__ sf, const float* __restrict__ bf_,
    float* __restrict__ out)
{
    int lane = threadIdx.x & 63, wave = threadIdx.x >> 6;
    int n0 = (blockIdx.x * 4 + wave) * 32;
    int ln = lane & 15, q = lane >> 4;

    uint4 araw[6][2];
#pragma unroll
    for (int kt = 0; kt < 6; kt++)
#pragma unroll
        for (int mt = 0; mt < 2; mt++)
            araw[kt][mt] = *(const uint4*)(msf + (long)(n0 + mt * 16 + ln) * 192 + kt * 32 + q * 8);

    f32x4 acc[2][4];
    for (int mt = 0; mt < 2; mt++) for (int nt = 0; nt < 4; nt++)
        acc[mt][nt] = (f32x4){0.f, 0.f, 0.f, 0.f};

#pragma unroll
    for (int kt = 0; kt < 6; kt++)
#pragma unroll
        for (int nt = 0; nt < 4; nt++) {
            f16x8 b = *(const f16x8*)(Wfst + ((nt * 16 + ln) * 192 + kt * 32 + q * 8));
#pragma unroll
            for (int mt = 0; mt < 2; mt++) {
                u4f16 v; v.u = araw[kt][mt];
                acc[mt][nt] = __builtin_amdgcn_mfma_f32_16x16x32_f16(v.h, b, acc[mt][nt], 0, 0, 0);
            }
        }

#pragma unroll
    for (int nt = 0; nt < 4; nt++) {
        int ch = nt * 16 + ln;
        float s = sf[ch], bb = bf_[ch];
#pragma unroll
        for (int mt = 0; mt < 2; mt++)
#pragma unroll
            for (int r = 0; r < 4; r++) {
                int n = n0 + mt * 16 + q * 4 + r;
                if (n < N_PTS)
                    out[(long)n * 64 + ch] = fmaxf(acc[mt][nt][r] * s + bb, 0.f);
            }
    }
}

// ---------------------------------------------------------------------------
extern "C" void kernel_launch(void* const* d_in, const int* in_sizes, int n_in,
                              void* d_out, int out_size, void* d_ws, size_t ws_size,
                              hipStream_t stream)
{
    const float* features = (const float*)d_in[0];
    const float* W1     = (const float*)d_in[1];
    const float* bn1_s  = (const float*)d_in[2];
    const float* bn1_b  = (const float*)d_in[3];
    const float* W2a    = (const float*)d_in[4];
    const float* bn2a_s = (const float*)d_in[5];
    const float* bn2a_b = (const float*)d_in[6];
    const float* W2b    = (const float*)d_in[7];
    const float* bn2b_s = (const float*)d_in[8];
    const float* bn2b_b = (const float*)d_in[9];
    const float* W3     = (const float*)d_in[10];
    const float* bn3_s  = (const float*)d_in[11];
    const float* bn3_b  = (const float*)d_in[12];
    const float* A1w    = (const float*)d_in[13];
    const float* A1b    = (const float*)d_in[14];
    const float* A2w    = (const float*)d_in[15];
    const float* A2b    = (const float*)d_in[16];
    const float* Wf     = (const float*)d_in[17];
    const float* bnf_s  = (const float*)d_in[18];
    const float* bnf_b  = (const float*)d_in[19];
    const int*   nbr1   = (const int*)d_in[20];
    const int*   nbr2   = (const int*)d_in[21];

    char* ws = (char*)d_ws;
    size_t off = 0;
    f16* featf = (f16*)(ws + off); off += (size_t)NPAD * 64 * 2;
    f16* hf    = (f16*)(ws + off); off += (size_t)NPAD * 32 * 2;
    f16* msf   = (f16*)(ws + off); off += (size_t)NPAD * 192 * 2;
    f16* Wt1   = (f16*)(ws + off); off += 9 * 64 * 64 * 2;
    f16* Wt3   = (f16*)(ws + off); off += 9 * 64 * 64 * 2;
    f16* Wt2b  = (f16*)(ws + off); off += 9 * 32 * 64 * 2;
    f16* Wfst  = (f16*)(ws + off); off += 192 * 64 * 2;
    float* pooled = (float*)(ws + off); off += 256 * 4;

    hipMemsetAsync(pooled, 0, 192 * sizeof(float), stream);

    k_head<<<HEAD_BLOCKS + WP_BLOCKS, 256, 0, stream>>>(
        features, W2a, bn2a_s, bn2a_b, W1, W2b, W3,
        featf, hf, Wt1, Wt2b, Wt3);
    // (NPAD/64)*3 units / 4 waves per block = 3516 blocks
    k_conv<<<(NPAD / 64) * 3 / 4, 256, 0, stream>>>(featf, hf, Wt1, Wt2b, Wt3, nbr1, nbr2,
                                           bn1_s, bn1_b, bn2b_s, bn2b_b, bn3_s, bn3_b,
                                           msf, pooled);
    k_attn<<<1, 256, 0, stream>>>(pooled, A1w, A1b, A2w, A2b, Wf, Wfst);
    k_fuse<<<NPAD / 128, 256, 0, stream>>>(msf, Wfst, bnf_s, bnf_b, (float*)d_out);
}